// Round 8
// baseline (43.521 us; speedup 1.0000x reference)
//
#include <hip/hip_runtime.h>

// Problem constants (from reference setup_inputs)
#define BB 32     // batch
#define UU 1152   // input_units
#define NN 10     // num_units
#define CC 8      // input_channels
#define DD 16     // channels_per_unit
#define EPS 1e-8f
#define INV_LN2 1.44269504088896341f

// inputs : (B, C, U)        float32
// weights: (U, N, C, D)     float32
// out    : (B, N, U, C, D)  float32
//
// R8: 8-wide lane split (2 lanes per (b,u,c)-group, 8 d-elements each):
//  - per-group issue cost drops ~22% vs quad split (scalar trans work
//    duplicated 2x not 4x; one DPP step per reduction instead of two)
//  - f32x4 vector math -> compiler can select packed v_pk_*_f32
//  - b-swizzled block order: blocks bi -> (b = bi&31, ublock = bi>>5), so all
//    32 batches sweep the SAME 40 KB weight slice concurrently -> L2-resident
//    weights; stores remain 2 KB contiguous per wave.
//  - explicit 3-deep weight prefetch (branchless) instead of unroll-2:
//    memory ILP without doubling live registers (~58 VGPR target).

typedef float f32x4 __attribute__((ext_vector_type(4)));

__device__ __forceinline__ float rcp_fast(float x) { return __builtin_amdgcn_rcpf(x); }
__device__ __forceinline__ float rsq_fast(float x) { return __builtin_amdgcn_rsqf(x); }

#if __has_builtin(__builtin_amdgcn_exp2f)
__device__ __forceinline__ float exp2_fast(float x) { return __builtin_amdgcn_exp2f(x); }
#else
__device__ __forceinline__ float exp2_fast(float x) { return __expf(x * 0.6931471805599453f); }
#endif

// sum across a lane PAIR (lanes 2k, 2k+1): one DPP xor-1 step
__device__ __forceinline__ float pair_sum(float x) {
    float y = __int_as_float(
        __builtin_amdgcn_update_dpp(0, __float_as_int(x), 0xB1, 0xF, 0xF, true)); // [1,0,3,2]
    return x + y;
}

__device__ __forceinline__ float hsum4(f32x4 a) {
    return (a.x + a.y) + (a.z + a.w);
}

__device__ __forceinline__ f32x4 exp2_v4(f32x4 a) {
    f32x4 r;
    r.x = exp2_fast(a.x); r.y = exp2_fast(a.y);
    r.z = exp2_fast(a.z); r.w = exp2_fast(a.w);
    return r;
}

__global__ __launch_bounds__(256) void caps_route_kernel(
    const float* __restrict__ inputs,
    const float* __restrict__ weights,
    float* __restrict__ out)
{
    int tid = threadIdx.x;
    int bi  = blockIdx.x;         // 2304 blocks = 32 b * 72 ublocks
    int b   = bi & 31;            // consecutive blocks share a u-slice of weights
    int ub  = bi >> 5;

    int sub    = tid & 1;         // low/high 8 elements of D
    int c      = (tid >> 1) & 7;
    int ulocal = tid >> 4;        // 0..15
    int u      = ub * 16 + ulocal;

    float v = inputs[(b * CC + c) * UU + u];

    const float* wbase = weights + (u * NN * CC + c) * DD + sub * 8;
    float*       obase = out + ((b * NN * UU + u) * CC + c) * DD + sub * 8;
    const int WSTRIDE = CC * DD;        // 128 floats between n-slices of weights
    const int OSTRIDE = UU * CC * DD;   // floats between n-slices of out

    // 3-deep prefetch pipeline for weight vectors
    f32x4 wa0 = *reinterpret_cast<const f32x4*>(wbase);
    f32x4 wb0 = *reinterpret_cast<const f32x4*>(wbase + 4);
    f32x4 wa1 = *reinterpret_cast<const f32x4*>(wbase + WSTRIDE);
    f32x4 wb1 = *reinterpret_cast<const f32x4*>(wbase + WSTRIDE + 4);

    #pragma unroll 1
    for (int n = 0; n < NN; ++n) {
        f32x4 wa = wa0, wb = wb0;
        wa0 = wa1; wb0 = wb1;
        int np = (n + 2 < NN) ? (n + 2) : (NN - 1);   // branchless clamp
        wa1 = *reinterpret_cast<const f32x4*>(wbase + np * WSTRIDE);
        wb1 = *reinterpret_cast<const f32x4*>(wbase + np * WSTRIDE + 4);

        f32x4 pa = wa * v, pb = wb * v;
        f32x4 qa = pa * pa, qb = pb * pb;

        // ---- iter 0 (folded): softmax uniform; L = scale0*INV_LN2/16 * q ----
        float sq0 = pair_sum(hsum4(qa + qb)) * (1.0f / 256.0f);
        float kk = sq0 * rcp_fast(1.0f + sq0) * rsq_fast(sq0 + EPS)
                   * (INV_LN2 / 16.0f);
        f32x4 La = kk * qa, Lb = kk * qb;

        // ---- iter 1 (base-2 logit update via m = e*q) ----
        {
            f32x4 ea = exp2_v4(La), eb = exp2_v4(Lb);
            float S = pair_sum(hsum4(ea + eb));
            f32x4 ma = ea * qa, mb = eb * qb;
            float A = pair_sum(hsum4(ma * ea + mb * eb));
            float Ssq = S * S;
            float k = A * rsq_fast(fmaf(EPS, Ssq, A)) * rcp_fast(Ssq + A)
                      * INV_LN2;
            La += k * ma;  Lb += k * mb;
        }

        // ---- iter 2 (final; logit update dead) ----
        {
            f32x4 ea = exp2_v4(La), eb = exp2_v4(Lb);
            float S = pair_sum(hsum4(ea + eb));
            f32x4 ta = ea * pa, tb = eb * pb;
            float A = pair_sum(hsum4(ta * ta + tb * tb));
            float Ssq = S * S;
            float ko = A * rsq_fast(fmaf(EPS, Ssq, A)) * rcp_fast(Ssq + A);
            *reinterpret_cast<f32x4*>(obase + n * OSTRIDE)     = ko * ta;
            *reinterpret_cast<f32x4*>(obase + n * OSTRIDE + 4) = ko * tb;
        }
    }
}

extern "C" void kernel_launch(void* const* d_in, const int* in_sizes, int n_in,
                              void* d_out, int out_size, void* d_ws, size_t ws_size,
                              hipStream_t stream) {
    const float* inputs  = (const float*)d_in[0];
    const float* weights = (const float*)d_in[1];
    float* out = (float*)d_out;

    const long long total = (long long)BB * UU * CC * 2;  // 589,824 = 2304*256
    const int block = 256;
    const int grid = (int)(total / block);                // exact
    caps_route_kernel<<<grid, block, 0, stream>>>(inputs, weights, out);
}